// Round 1
// baseline (149.390 us; speedup 1.0000x reference)
//
#include <hip/hip_runtime.h>
#include <hip/hip_bf16.h>
#include <math.h>

// Problem constants (B=16, L=256, D=256, K=16384)
#define NROWS 4096               // B*L anchors / z rows
#define KMEM  16384
#define NCAND 20480              // NROWS + KMEM candidates
#define DIM   256                // feature dim
#define BM    256                // anchor rows per block
#define BN    256                // candidate cols per tile
#define BK    64                 // k-depth per K-tile (bf16)
#define NSLICE 16                // 16 rowblocks x 16 slices = 256 blocks = 1/CU
#define COLS_PER_SLICE (NCAND / NSLICE)        // 1280
#define TILES_PER_SLICE (COLS_PER_SLICE / BN)  // 5
#define NKT (TILES_PER_SLICE * 4)              // 20 K-tiles per block (D=256 -> 4/tile)
#define REGION 16384             // one LDS region: 256 rows x 32 bf16 (64B/row)
#define INV_T  (1.0f / 0.07f)
#define SCALE2 (1.4426950408889634f / 0.07f)  // log2(e)/T
#define LN2 0.6931471805599453f
#define MERGE_STRIDE 33          // conflict-free merge overlay

typedef short  short8 __attribute__((ext_vector_type(8)));  // 8 bf16 (4 VGPRs)
typedef float  f32x4  __attribute__((ext_vector_type(4)));  // MFMA C/D
typedef unsigned short ushort_t;

#define BARRIER() asm volatile("s_barrier" ::: "memory")

// RNE float->bf16 (inputs are finite normals; no NaN path needed)
__device__ inline ushort_t f2bf(float x) {
    union { float f; unsigned u; } a; a.f = x;
    unsigned r = a.u + 0x7fff + ((a.u >> 16) & 1);
    return (ushort_t)(r >> 16);
}

// async global->LDS, 16B per lane, dest = wave-uniform base + lane*16
__device__ inline void load_lds16(const ushort_t* g, char* l) {
    __builtin_amdgcn_global_load_lds(
        (const __attribute__((address_space(1))) unsigned int*)g,
        (__attribute__((address_space(3))) unsigned int*)l, 16, 0, 0);
}

// Kernel 0: cast fp32 -> bf16 into cand = [z ; mem]; zero loss accumulator.
__global__ __launch_bounds__(256) void cast_kernel(
    const float* __restrict__ z, const float* __restrict__ mem,
    ushort_t* __restrict__ cand, float* __restrict__ acc_ct)
{
    if (blockIdx.x == 0 && threadIdx.x == 0) {
        acc_ct[0] = 0.0f;                      // loss accumulator
        ((unsigned*)acc_ct)[1] = 0u;           // arrival counter
    }
    const int idx = blockIdx.x * 256 + threadIdx.x;  // float4 index, < 1310720
    const int ZQ = NROWS * DIM / 4;                  // 262144
    const float4 v = (idx < ZQ) ? ((const float4*)z)[idx]
                                : ((const float4*)mem)[idx - ZQ];
    ushort4 u; u.x = f2bf(v.x); u.y = f2bf(v.y); u.z = f2bf(v.z); u.w = f2bf(v.w);
    ((ushort4*)cand)[idx] = u;
}

// Kernel A: 256x256-tile, 8-wave, 4-phase-per-K-tile MFMA flash-LSE.
//
// LDS: 2 buffers x 4 regions x 16KB = 128KB. Region r of buffer b at
// (b*4+r)*16384: r0=A-ks0, r1=B-ks0, r2=A-ks1, r3=B-ks1 (ks = 32-wide k-slice
// of the BK=64 K-tile). Each region: 256 rows x 32 bf16, row stride 64B, with
// 16B-slot XOR swizzle slot' = slot ^ ((row>>1)&3) (read-side swizzle +
// inverse-swizzled GLOBAL source; LDS dest of global_load_lds stays linear).
//
// Per K-tile kt (buffer b=kt&1), 4 phases, 16 MFMA each:
//   p1: ks0/cols 0-63   reads r0,r1(b); stages A-ks1(kt+1) -> r2(b^1)
//   p2: ks0/cols 64-127 reads r1(b);    stages B-ks1(kt+1) -> r3(b^1); vmcnt(8)
//   p3: ks1/cols 0-63   reads r2,r3(b); stages A-ks0(kt+2) -> r0(b)
//   p4: ks1/cols 64-127 reads r3(b);    stages B-ks0(kt+2) -> r1(b);   vmcnt(8)
// Each phase: {ds_read frags; issue stage; s_barrier; MFMA under setprio(1);
// s_barrier}. Write-safety: a region's readers all pass the reading phase's
// final barrier before the (later-phase) stage that overwrites it. vmcnt(8)
// = exactly 4 half-tiles (one K-tile of data) stay in flight across every
// barrier -- never drained to 0 in the loop. Tail stages (G>=NKT) clamp the
// source address and land in dead regions so the counts stay uniform.
__global__ __launch_bounds__(512) void mfma_lse_kernel(
    const ushort_t* __restrict__ cand,
    float* __restrict__ part_m, float* __restrict__ part_s)
{
    __shared__ __align__(16) char smem[131072];

    const int tid  = threadIdx.x;
    const int lane = tid & 63;
    const int w    = tid >> 6;        // wave 0..7
    const int wm   = w >> 1;          // wave row group (0..3), 64 rows each
    const int wn   = w & 1;           // wave col group (0..1), 128 cols each
    const int quad = lane >> 4;
    const int ln   = lane & 15;

    // XCD-chunked swizzle: XCD j (= bid&7 under round-robin dispatch) owns
    // slices {2j,2j+1} x all 16 rowblocks -> B working set ~1.3MB fits L2.
    const int bid = blockIdx.x;
    const int bq  = bid >> 3;
    const int slice = (bid & 7) * 2 + (bq >> 4);
    const int bx    = bq & 15;
    const int rowBase = bx * BM;
    const int colSliceBase = slice * COLS_PER_SLICE;

    // ds_read addressing: frag (row=base+ln, k-chunk=quad) at byte
    // row*64 + (quad ^ ((row>>1)&3))*16; (row>>1)&3 == (ln>>1)&3 since all
    // row bases are multiples of 16. Wave's 64 lanes cover 16 rows x 4 slots
    // exactly once -> uniform 2-accesses/bank (free, m136).
    const int swz    = (quad ^ ((ln >> 1) & 3)) << 4;
    const int dsAoff = (wm * 64 + ln) * 64 + swz;
    const int dsBoff = REGION + (wn * 128 + ln) * 64 + swz;

    // staging: lane l of load u covers region row (w*2+u)*16 + (l>>2),
    // physical slot l&3 -> must FETCH global k-chunk (l&3) ^ ((row>>1)&3),
    // with (row>>1)&3 == (l>>3)&3 (row base multiple of 16).
    const int srow   = w * 32 + (lane >> 2);              // u=0 row
    const int kchunk = (lane & 3) ^ ((lane >> 3) & 3);
    const unsigned srcAoff = (unsigned)(rowBase + srow) * DIM + kchunk * 8;
    const unsigned srcBoff = (unsigned)(colSliceBase + srow) * DIM + kchunk * 8;
    const int dstOff = w * 2048;                          // (w*2)*1024, wave-uniform

    auto stage = [&](int G, int ks, int isB) {            // one 16KB half-tile
        const int Gc = (G < NKT) ? G : (NKT - 1);         // tail: clamp src only
        const int kb = ((Gc & 3) << 6) + (ks << 5);       // element k-offset
        const unsigned src =
            (isB ? srcBoff + ((unsigned)(Gc >> 2) << 16) : srcAoff) + kb;
        char* dst = smem + (((G & 1) << 2) + (ks << 1) + isB) * REGION + dstOff;
        load_lds16(cand + src, dst);                      // rows +0..15
        load_lds16(cand + src + 16 * DIM, dst + 1024);    // rows +16..31
    };

    float m2[16], s[16];
#pragma unroll
    for (int i = 0; i < 16; ++i) { m2[i] = -INFINITY; s[i] = 0.0f; }

    f32x4 acc[4][8];
#pragma unroll
    for (int i = 0; i < 4; ++i)
#pragma unroll
        for (int j = 0; j < 8; ++j) acc[i][j] = (f32x4)0.0f;

    // prologue: K-tile 0 fully + K-tile 1's ks0 half; keep 8 loads in flight
    stage(0, 0, 0); stage(0, 0, 1); stage(0, 1, 0); stage(0, 1, 1);
    stage(1, 0, 0); stage(1, 0, 1);
    asm volatile("s_waitcnt vmcnt(8)" ::: "memory");      // r0(0),r1(0) landed
    BARRIER();

#pragma unroll 1
    for (int t = 0; t < TILES_PER_SLICE; ++t) {
#pragma unroll 1
        for (int k4 = 0; k4 < 4; ++k4) {
            const int kt = t * 4 + k4;
            const char* pA = smem + ((kt & 1) << 16) + dsAoff;
            const char* pB = smem + ((kt & 1) << 16) + dsBoff;
            short8 a[4], b[4];

            // ---- phase 1: ks0, wave cols 0-63
#pragma unroll
            for (int i = 0; i < 4; ++i) a[i] = *(const short8*)(pA + i * 1024);
#pragma unroll
            for (int j = 0; j < 4; ++j) b[j] = *(const short8*)(pB + j * 1024);
            stage(kt + 1, 1, 0);
            BARRIER();
            __builtin_amdgcn_s_setprio(1);
            __builtin_amdgcn_sched_barrier(0);
#pragma unroll
            for (int i = 0; i < 4; ++i)
#pragma unroll
                for (int j = 0; j < 4; ++j)
                    acc[i][j] = __builtin_amdgcn_mfma_f32_16x16x32_bf16(
                        a[i], b[j], acc[i][j], 0, 0, 0);
            __builtin_amdgcn_sched_barrier(0);
            __builtin_amdgcn_s_setprio(0);
            BARRIER();

            // ---- phase 2: ks0, wave cols 64-127 (A frags reused)
#pragma unroll
            for (int j = 0; j < 4; ++j) b[j] = *(const short8*)(pB + 4096 + j * 1024);
            stage(kt + 1, 1, 1);
            BARRIER();
            __builtin_amdgcn_s_setprio(1);
            __builtin_amdgcn_sched_barrier(0);
#pragma unroll
            for (int i = 0; i < 4; ++i)
#pragma unroll
                for (int j = 0; j < 4; ++j)
                    acc[i][4 + j] = __builtin_amdgcn_mfma_f32_16x16x32_bf16(
                        a[i], b[j], acc[i][4 + j], 0, 0, 0);
            __builtin_amdgcn_sched_barrier(0);
            __builtin_amdgcn_s_setprio(0);
            asm volatile("s_waitcnt vmcnt(8)" ::: "memory");  // r2,r3(kt) landed
            BARRIER();

            // ---- phase 3: ks1, wave cols 0-63
#pragma unroll
            for (int i = 0; i < 4; ++i) a[i] = *(const short8*)(pA + 32768 + i * 1024);
#pragma unroll
            for (int j = 0; j < 4; ++j) b[j] = *(const short8*)(pB + 32768 + j * 1024);
            stage(kt + 2, 0, 0);
            BARRIER();
            __builtin_amdgcn_s_setprio(1);
            __builtin_amdgcn_sched_barrier(0);
#pragma unroll
            for (int i = 0; i < 4; ++i)
#pragma unroll
                for (int j = 0; j < 4; ++j)
                    acc[i][j] = __builtin_amdgcn_mfma_f32_16x16x32_bf16(
                        a[i], b[j], acc[i][j], 0, 0, 0);
            __builtin_amdgcn_sched_barrier(0);
            __builtin_amdgcn_s_setprio(0);
            BARRIER();

            // ---- phase 4: ks1, wave cols 64-127
#pragma unroll
            for (int j = 0; j < 4; ++j)
                b[j] = *(const short8*)(pB + 32768 + 4096 + j * 1024);
            stage(kt + 2, 0, 1);
            BARRIER();
            __builtin_amdgcn_s_setprio(1);
            __builtin_amdgcn_sched_barrier(0);
#pragma unroll
            for (int i = 0; i < 4; ++i)
#pragma unroll
                for (int j = 0; j < 4; ++j)
                    acc[i][4 + j] = __builtin_amdgcn_mfma_f32_16x16x32_bf16(
                        a[i], b[j], acc[i][4 + j], 0, 0, 0);
            __builtin_amdgcn_sched_barrier(0);
            __builtin_amdgcn_s_setprio(0);
            asm volatile("s_waitcnt vmcnt(8)" ::: "memory");  // r0,r1(kt+1) landed
            BARRIER();
        }

        // Online-LSE epilogue for candidate tile t (next tile's loads in flight).
        // C/D layout: col = colBase + wn*128 + tj*16 + ln,
        //             row = rowBase + wm*64 + ti*16 + quad*4 + r.
        {
            const int colBase = colSliceBase + t * BN;
            const int diag = (colBase == rowBase);   // tiles 256-aligned both ways
            const int lcol0 = wn * 128 + ln;
#pragma unroll
            for (int ti = 0; ti < 4; ++ti) {
#pragma unroll
                for (int r = 0; r < 4; ++r) {
                    const int idx = ti * 4 + r;
                    float v[8];
#pragma unroll
                    for (int j = 0; j < 8; ++j) v[j] = acc[ti][j][r];
                    if (diag) {
                        const int lrow = wm * 64 + ti * 16 + quad * 4 + r;
#pragma unroll
                        for (int j = 0; j < 8; ++j)
                            if (lcol0 + j * 16 == lrow) v[j] = -3.0e38f;
                    }
                    const float t0 = fmaxf(fmaxf(v[0], v[1]), fmaxf(v[2], v[3]));
                    const float t1 = fmaxf(fmaxf(v[4], v[5]), fmaxf(v[6], v[7]));
                    const float tmax = fmaxf(t0, t1) * SCALE2;
                    const float mo = m2[idx];
                    const float mn = fmaxf(mo, tmax);
                    float sum = __builtin_amdgcn_exp2f(fmaf(v[0], SCALE2, -mn));
#pragma unroll
                    for (int j = 1; j < 8; ++j)
                        sum += __builtin_amdgcn_exp2f(fmaf(v[j], SCALE2, -mn));
                    s[idx] = s[idx] * __builtin_amdgcn_exp2f(mo - mn) + sum;
                    m2[idx] = mn;
#pragma unroll
                    for (int j = 0; j < 8; ++j) acc[ti][j][r] = 0.0f;
                }
            }
        }
    }

    // Drain tail garbage stages before reusing LDS, then cross-lane merge:
    // 32 partials per row (16 ln x 2 wn), stride-33 overlay.
    asm volatile("s_waitcnt vmcnt(0)" ::: "memory");
    BARRIER();
    float* smf = (float*)smem;                 // [256][33] m partials
    float* ssf = smf + BM * MERGE_STRIDE;      // [256][33] s partials
    const int p = wn * 16 + ln;
#pragma unroll
    for (int ti = 0; ti < 4; ++ti)
#pragma unroll
        for (int r = 0; r < 4; ++r) {
            const int rl = wm * 64 + ti * 16 + quad * 4 + r;
            smf[rl * MERGE_STRIDE + p] = m2[ti * 4 + r];
            ssf[rl * MERGE_STRIDE + p] = s[ti * 4 + r];
        }
    __syncthreads();
    if (tid < BM) {
        float M = -INFINITY;
#pragma unroll
        for (int x = 0; x < 32; ++x) M = fmaxf(M, smf[tid * MERGE_STRIDE + x]);
        float S = 0.0f;
#pragma unroll
        for (int x = 0; x < 32; ++x)
            S += ssf[tid * MERGE_STRIDE + x]
               * __builtin_amdgcn_exp2f(smf[tid * MERGE_STRIDE + x] - M);
        part_m[(size_t)(rowBase + tid) * NSLICE + slice] = M;
        part_s[(size_t)(rowBase + tid) * NSLICE + slice] = S;
    }
}

// Kernel F: fused pos-dot + slice combine + loss reduce. Wave-per-row:
// 1024 blocks x 256 threads (4 rows/block), coalesced float4 dot + butterfly.
__global__ __launch_bounds__(256) void final_kernel(
    const float* __restrict__ z,
    const float* __restrict__ part_m, const float* __restrict__ part_s,
    float* __restrict__ acc_ct, float* __restrict__ out)
{
    __shared__ float red[4];
    const int tid = threadIdx.x;
    const int wv = tid >> 6, lane = tid & 63;
    const int i = blockIdx.x * 4 + wv;          // row 0..4095 (wave-uniform)
    float local = 0.0f;
    if ((i & 255) != 255) {                     // valid pair (also guards i=4095)
        // exact fp32 dot(z[i], z[i+1]): one float4 per lane, full-wave butterfly
        const float4 av = ((const float4*)(z + (size_t)i * DIM))[lane];
        const float4 bv = ((const float4*)(z + (size_t)(i + 1) * DIM))[lane];
        float d = av.x * bv.x + av.y * bv.y + av.z * bv.z + av.w * bv.w;
#pragma unroll
        for (int off = 32; off > 0; off >>= 1) d += __shfl_xor(d, off);
        // slice merge on lanes 0..15
        const float m  = (lane < NSLICE) ? part_m[(size_t)i * NSLICE + lane] : -INFINITY;
        const float sv = (lane < NSLICE) ? part_s[(size_t)i * NSLICE + lane] : 0.0f;
        float M = m;
#pragma unroll
        for (int off = 8; off > 0; off >>= 1) M = fmaxf(M, __shfl_xor(M, off));
        float S = (lane < NSLICE) ? sv * __builtin_amdgcn_exp2f(m - M) : 0.0f;
#pragma unroll
        for (int off = 8; off > 0; off >>= 1) S += __shfl_xor(S, off);
        const float lse = LN2 * (M + __builtin_amdgcn_logf(S));  // v_log = log2
        local = lse - d * INV_T;
    }
    if (lane == 0) red[wv] = local;
    __syncthreads();
    if (tid == 0) {
        const float r = red[0] + red[1] + red[2] + red[3];
        atomicAdd(&acc_ct[0], r);               // device-scope float atomic
        __threadfence();
        const unsigned old = atomicAdd((unsigned*)&acc_ct[1], 1u);
        if (old == gridDim.x - 1) {
            const float total = atomicAdd(&acc_ct[0], 0.0f);  // coherent read
            out[0] = total / 4080.0f;           // B*(L-1) valid pairs
        }
    }
}

extern "C" void kernel_launch(void* const* d_in, const int* in_sizes, int n_in,
                              void* d_out, int out_size, void* d_ws, size_t ws_size,
                              hipStream_t stream) {
    const float* z   = (const float*)d_in[0];   // [4096, 256]
    // d_in[1] = va_values: dead code in the reference, unused.
    const float* mem = (const float*)d_in[2];   // [16384, 256]

    // ws layout: cand bf16 [20480*256] | part_m f32 [4096*16]
    //          | part_s f32 [4096*16] | acc_ct f32[2]
    ushort_t* cand = (ushort_t*)d_ws;
    float* part_m  = (float*)(cand + (size_t)NCAND * DIM);
    float* part_s  = part_m + (size_t)NROWS * NSLICE;
    float* acc_ct  = part_s + (size_t)NROWS * NSLICE;

    const int castBlocks = NCAND * DIM / 4 / 256;   // 5120
    cast_kernel<<<dim3(castBlocks), dim3(256), 0, stream>>>(z, mem, cand, acc_ct);
    mfma_lse_kernel<<<dim3(256), dim3(512), 0, stream>>>(cand, part_m, part_s);
    final_kernel<<<dim3(NROWS / 4), dim3(256), 0, stream>>>(
        z, part_m, part_s, acc_ct, (float*)d_out);
}